// Round 10
// baseline (315.200 us; speedup 1.0000x reference)
//
#include <hip/hip_runtime.h>
#include <hip/hip_bf16.h>
#include <math.h>

typedef __bf16 bf16x8 __attribute__((ext_vector_type(8)));
typedef __bf16 bf16x4 __attribute__((ext_vector_type(4)));
typedef float  f32x4  __attribute__((ext_vector_type(4)));
typedef short  s16x8  __attribute__((ext_vector_type(8)));

#define N_TOK  4096
#define DMODEL 1024
#define NHEAD  4
#define DHEAD  256

__device__ __forceinline__ f32x4 mfma16x16(bf16x8 a, bf16x8 b, f32x4 c) {
    return __builtin_amdgcn_mfma_f32_16x16x32_bf16(a, b, c, 0, 0, 0);
}

// async global->LDS, 16B per lane; LDS dest = wave-uniform base + lane*16
__device__ __forceinline__ void gload_lds16(const void* gsrc, void* ldst) {
    __builtin_amdgcn_global_load_lds(
        (const __attribute__((address_space(1))) void*)gsrc,
        (__attribute__((address_space(3))) void*)ldst, 16, 0, 0);
}

// ---- batched fp32 -> bf16 convert (q,k,v), 8 elem/thread
struct CvtArgs { const float* src[3]; __bf16* dst[3]; };
__global__ __launch_bounds__(256)
void cvt_bf16_kernel(CvtArgs a)
{
    const float* in = a.src[blockIdx.y];
    __bf16* out = a.dst[blockIdx.y];
    size_t i8 = ((size_t)blockIdx.x * 256 + threadIdx.x) * 8;
    f32x4 t0 = *(const f32x4*)(in + i8);
    f32x4 t1 = *(const f32x4*)(in + i8 + 4);
    bf16x8 b;
    #pragma unroll
    for (int j = 0; j < 4; ++j) { b[j] = (__bf16)t0[j]; b[j + 4] = (__bf16)t1[j]; }
    *(bf16x8*)(out + i8) = b;
}

// ---- weight transpose+convert: in [1024][C] fp32 -> out [C][1024] bf16
__device__ __forceinline__ void transposew_body(const float* __restrict__ in,
                                                __bf16* __restrict__ out, int C)
{
    __shared__ __align__(16) __bf16 tile[64 * 72];
    const int tid = threadIdx.x;
    const int r0 = blockIdx.x * 64;
    const int c0 = blockIdx.y * 64;
    if (c0 >= C) return;
    #pragma unroll
    for (int it = 0; it < 4; ++it) {
        int i = tid + it * 256;
        int row = i >> 4, c4 = i & 15;
        f32x4 v = *(const f32x4*)(in + (size_t)(r0 + row) * C + c0 + c4 * 4);
        #pragma unroll
        for (int j = 0; j < 4; ++j)
            tile[(c4 * 4 + j) * 72 + row] = (__bf16)v[j];
    }
    __syncthreads();
    #pragma unroll
    for (int it = 0; it < 2; ++it) {
        int i = tid + it * 256;
        int col = i >> 3, ch = i & 7;
        s16x8 v = *(const s16x8*)(&tile[col * 72 + ch * 8]);
        *(s16x8*)((short*)out + (size_t)(c0 + col) * 1024 + r0 + ch * 8) = v;
    }
}

__global__ __launch_bounds__(256)
void transposew_kernel(const float* __restrict__ in, __bf16* __restrict__ out, int C)
{
    transposew_body(in, out, C);
}

struct TWArgs { const float* src[4]; __bf16* dst[4]; int C[4]; };
__global__ __launch_bounds__(256)
void transposew_batch_kernel(TWArgs a)
{
    int z = blockIdx.z;
    transposew_body(a.src[z], a.dst[z], a.C[z]);
}

// ---- FUSED bt-GEMM batch (unchanged from R9): 128x128 tile, 832 blocks
struct GemmDesc {
    const __bf16* A; const __bf16* B; const float* bias; __bf16* C;
    int lda, ldb, ldc, gx, nblocks, relu, biasrow; float scale;
};
struct FusedArgs { GemmDesc d[4]; };

__global__ __launch_bounds__(256, 2)
void gemm_fused(FusedArgs fa)
{
    __shared__ __align__(16) short As[2][128 * 64];
    __shared__ __align__(16) short Bs[2][128 * 64];

    int b = blockIdx.x, z = 0;
    while (b >= fa.d[z].nblocks) { b -= fa.d[z].nblocks; ++z; }
    const GemmDesc D = fa.d[z];
    const int m0 = (b % D.gx) * 128;
    const int n0 = (b / D.gx) * 128;

    const int tid  = threadIdx.x;
    const int lane = tid & 63;
    const int wv   = tid >> 6;
    const int c16  = lane & 15;
    const int quad = lane >> 4;
    const int swz  = c16 & 7;
    const int wr   = wv >> 1;
    const int wc   = wv & 1;

    f32x4 acc[4][4];
    #pragma unroll
    for (int i = 0; i < 4; ++i)
        #pragma unroll
        for (int j = 0; j < 4; ++j)
            acc[i][j] = (f32x4){0.f, 0.f, 0.f, 0.f};

    const int sRow = lane >> 3;
    const int sCh  = (lane & 7) ^ (sRow & 7);

    auto issue = [&](short* Abuf, short* Bbuf, int k0) {
        #pragma unroll
        for (int g = 0; g < 4; ++g) {
            int row = 32 * wv + 8 * g + sRow;
            const char* src = (const char*)(D.A + (size_t)(m0 + row) * D.lda + k0) + sCh * 16;
            gload_lds16(src, (char*)Abuf + (32 * wv + 8 * g) * 128);
        }
        #pragma unroll
        for (int g = 0; g < 4; ++g) {
            int row = 32 * wv + 8 * g + sRow;
            const char* src = (const char*)(D.B + (size_t)(n0 + row) * D.ldb + k0) + sCh * 16;
            gload_lds16(src, (char*)Bbuf + (32 * wv + 8 * g) * 128);
        }
    };
    auto compute = [&](const short* Abuf, const short* Bbuf) {
        __builtin_amdgcn_s_setprio(1);
        #pragma unroll
        for (int ks = 0; ks < 2; ++ks) {
            bf16x8 af[4], bfr[4];
            int slot = ((ks * 4 + quad) ^ swz) * 16;
            #pragma unroll
            for (int t = 0; t < 4; ++t)
                af[t] = *(const bf16x8*)((const char*)Abuf + (wr * 64 + t * 16 + c16) * 128 + slot);
            #pragma unroll
            for (int t = 0; t < 4; ++t)
                bfr[t] = *(const bf16x8*)((const char*)Bbuf + (wc * 64 + t * 16 + c16) * 128 + slot);
            #pragma unroll
            for (int tm = 0; tm < 4; ++tm)
                #pragma unroll
                for (int tn = 0; tn < 4; ++tn)
                    acc[tm][tn] = mfma16x16(af[tm], bfr[tn], acc[tm][tn]);
        }
        __builtin_amdgcn_s_setprio(0);
    };

    issue(As[0], Bs[0], 0);
    __syncthreads();

    #pragma unroll 1
    for (int t = 0; t < 16; t += 2) {
        if (t + 1 < 16) issue(As[1], Bs[1], (t + 1) << 6);
        compute(As[0], Bs[0]);
        __syncthreads();
        if (t + 2 < 16) issue(As[0], Bs[0], (t + 2) << 6);
        compute(As[1], Bs[1]);
        __syncthreads();
    }

    #pragma unroll
    for (int tm = 0; tm < 4; ++tm) {
        #pragma unroll
        for (int rr = 0; rr < 4; ++rr) {
            int row = m0 + wr * 64 + tm * 16 + quad * 4 + rr;
            float rbv = D.biasrow ? D.bias[row] : 0.0f;
            #pragma unroll
            for (int tn = 0; tn < 4; ++tn) {
                int col = n0 + wc * 64 + tn * 16 + c16;
                float bb = D.biasrow ? rbv : D.bias[col];
                float val = (acc[tm][tn][rr] + bb) * D.scale;
                if (D.relu) val = fmaxf(val, 0.0f);
                D.C[(size_t)row * D.ldc + col] = (__bf16)val;
            }
        }
    }
}

// ---- bt-GEMM (out-projection, unchanged from R9)
template<typename OutT, bool BIASROW>
__global__ __launch_bounds__(256, 2)
void gemm_bt(const __bf16* __restrict__ A, int lda,
             const __bf16* __restrict__ B, int ldb,
             const float* __restrict__ bias,
             OutT* __restrict__ C, int ldc,
             float scale, int relu, const float* __restrict__ rowmask, int K)
{
    __shared__ __align__(16) short As[2][128 * 64];
    __shared__ __align__(16) short Bs[2][128 * 64];
    const int tid  = threadIdx.x;
    const int lane = tid & 63;
    const int wv   = tid >> 6;
    const int c16  = lane & 15;
    const int quad = lane >> 4;
    const int swz  = c16 & 7;
    const int wr   = wv >> 1;
    const int wc   = wv & 1;
    const int m0 = blockIdx.x * 128;
    const int n0 = blockIdx.y * 128;

    f32x4 acc[4][4];
    #pragma unroll
    for (int i = 0; i < 4; ++i)
        #pragma unroll
        for (int j = 0; j < 4; ++j)
            acc[i][j] = (f32x4){0.f, 0.f, 0.f, 0.f};

    const int sRow = lane >> 3;
    const int sCh  = (lane & 7) ^ (sRow & 7);

    auto issue = [&](short* Abuf, short* Bbuf, int k0) {
        #pragma unroll
        for (int g = 0; g < 4; ++g) {
            int row = 32 * wv + 8 * g + sRow;
            const char* src = (const char*)(A + (size_t)(m0 + row) * lda + k0) + sCh * 16;
            gload_lds16(src, (char*)Abuf + (32 * wv + 8 * g) * 128);
        }
        #pragma unroll
        for (int g = 0; g < 4; ++g) {
            int row = 32 * wv + 8 * g + sRow;
            const char* src = (const char*)(B + (size_t)(n0 + row) * ldb + k0) + sCh * 16;
            gload_lds16(src, (char*)Bbuf + (32 * wv + 8 * g) * 128);
        }
    };
    auto compute = [&](const short* Abuf, const short* Bbuf) {
        __builtin_amdgcn_s_setprio(1);
        #pragma unroll
        for (int ks = 0; ks < 2; ++ks) {
            bf16x8 af[4], bfr[4];
            int slot = ((ks * 4 + quad) ^ swz) * 16;
            #pragma unroll
            for (int t = 0; t < 4; ++t)
                af[t] = *(const bf16x8*)((const char*)Abuf + (wr * 64 + t * 16 + c16) * 128 + slot);
            #pragma unroll
            for (int t = 0; t < 4; ++t)
                bfr[t] = *(const bf16x8*)((const char*)Bbuf + (wc * 64 + t * 16 + c16) * 128 + slot);
            #pragma unroll
            for (int tm = 0; tm < 4; ++tm)
                #pragma unroll
                for (int tn = 0; tn < 4; ++tn)
                    acc[tm][tn] = mfma16x16(af[tm], bfr[tn], acc[tm][tn]);
        }
        __builtin_amdgcn_s_setprio(0);
    };

    const int nt = K >> 6;
    issue(As[0], Bs[0], 0);
    __syncthreads();

    #pragma unroll 1
    for (int t = 0; t < nt; t += 2) {
        if (t + 1 < nt) issue(As[1], Bs[1], (t + 1) << 6);
        compute(As[0], Bs[0]);
        __syncthreads();
        if (t + 1 < nt) {
            if (t + 2 < nt) issue(As[0], Bs[0], (t + 2) << 6);
            compute(As[1], Bs[1]);
            __syncthreads();
        }
    }

    #pragma unroll
    for (int tm = 0; tm < 4; ++tm) {
        #pragma unroll
        for (int rr = 0; rr < 4; ++rr) {
            int row = m0 + wr * 64 + tm * 16 + quad * 4 + rr;
            float mk = rowmask ? rowmask[row] : 1.0f;
            float rbv = BIASROW ? bias[row] : 0.0f;
            #pragma unroll
            for (int tn = 0; tn < 4; ++tn) {
                int col = n0 + wc * 64 + tn * 16 + c16;
                float b = BIASROW ? rbv : bias[col];
                float val = (acc[tm][tn][rr] + b) * scale;
                if (relu) val = fmaxf(val, 0.0f);
                val *= mk;
                C[(size_t)row * ldc + col] = (OutT)val;
            }
        }
    }
}

// ---- scores -> mask (unchanged)
__global__ void score_mask_kernel(const __bf16* __restrict__ h,
                                  const float* __restrict__ w2,
                                  const float* __restrict__ b2,
                                  float* __restrict__ maskf)
{
    int lane = threadIdx.x & 63;
    int tok  = blockIdx.x * 4 + (threadIdx.x >> 6);
    const __bf16* hr = h + (size_t)tok * 256;
    float s = 0.f;
    #pragma unroll
    for (int j = 0; j < 4; ++j) {
        int c = j * 64 + lane;
        s += (float)hr[c] * w2[c];
    }
    #pragma unroll
    for (int o = 1; o < 64; o <<= 1) s += __shfl_xor(s, o);
    if (lane == 0) {
        float x = s + b2[0];
        maskf[tok] = (x > -1.7346010553881064f) ? 1.0f : 0.0f;
    }
}

// ---- flash attention, QBLK=256: 8 waves x 32 q-rows (2 subtiles of 16),
// shared K/V fragment reads (each b128 feeds 2 MFMAs). Ps rows padded to
// 72 shorts (144B): quad stride 576B = 16 banks -> ~2-way writes (free).
// K single-buffer (prefetch issued in PV segment), V dbuf (issued in QK
// segment) - each load drains at a barrier it hides behind. LDS 132 KB.
// Grid 256 = (16 qb, 4 head, 4 ksp), XCD-clustered. 4-way split + combine.
__global__ __launch_bounds__(512, 1)
void attn_kernel(const __bf16* __restrict__ qp, const __bf16* __restrict__ kp,
                 const __bf16* __restrict__ vpT, const float* __restrict__ maskf,
                 __bf16* __restrict__ O0, __bf16* __restrict__ O1,
                 __bf16* __restrict__ O2, __bf16* __restrict__ O3,
                 float* __restrict__ lbuf)
{
    __shared__ __align__(16) short Ks[64 * 256];       // 32 KB single
    __shared__ __align__(16) short Vs[2][256 * 64];    // 64 KB dbuf
    __shared__ __align__(16) short PsA[8 * 32 * 72];   // 36 KB padded

    const int tid  = threadIdx.x;
    const int lane = tid & 63;
    const int wv   = tid >> 6;       // 0..7
    const int c16  = lane & 15;
    const int quad = lane >> 4;
    const int swz  = c16 & 7;

    const int d    = blockIdx.x;     // 0..255
    const int g    = d & 7;          // XCD
    const int tt   = d >> 3;         // 0..31
    const int head = g >> 1;
    const int ksp  = (g & 1) * 2 + (tt >> 4);
    const int qb   = tt & 15;
    const int kbase = ksp * 1024;
    const int q0w  = qb * 256 + wv * 32;
    short* Ps = PsA + wv * 32 * 72;
    __bf16* Ob = (ksp == 0) ? O0 : (ksp == 1) ? O1 : (ksp == 2) ? O2 : O3;

    // Q fragments for both 16-row subtiles (A-layout: m=lane&15, k=quad*8+j)
    bf16x8 qf[2][8];
    #pragma unroll
    for (int sub = 0; sub < 2; ++sub)
        #pragma unroll
        for (int c = 0; c < 8; ++c)
            qf[sub][c] = *(const bf16x8*)(qp + (size_t)(q0w + sub * 16 + c16) * DMODEL + head * DHEAD + c * 32 + quad * 8);

    f32x4 o[2][16];
    #pragma unroll
    for (int sub = 0; sub < 2; ++sub)
        #pragma unroll
        for (int t = 0; t < 16; ++t) o[sub][t] = (f32x4){0.f, 0.f, 0.f, 0.f};
    float psum[2][4] = {{0.f, 0.f, 0.f, 0.f}, {0.f, 0.f, 0.f, 0.f}};

    const int kRow0 = wv * 8 + (lane >> 5);
    const int kCh   = lane & 31;
    const int vRow0 = wv * 32 + (lane >> 3);
    const int vCh   = (lane & 7) ^ ((lane >> 3) & 7);

    auto issueK = [&](int n0) {
        #pragma unroll
        for (int gg = 0; gg < 4; ++gg) {
            int key = kRow0 + gg * 2;
            int c   = kCh ^ (key & 7);
            const char* src = (const char*)(kp + (size_t)(n0 + key) * DMODEL + head * DHEAD) + c * 16;
            gload_lds16(src, (char*)Ks + (wv * 8 + gg * 2) * 512);
        }
    };
    auto issueV = [&](int buf, int n0) {
        #pragma unroll
        for (int gg = 0; gg < 4; ++gg) {
            int row = vRow0 + gg * 8;
            const char* src = (const char*)(vpT + (size_t)(head * DHEAD + row) * N_TOK + n0) + vCh * 16;
            gload_lds16(src, (char*)Vs[buf] + (wv * 32 + gg * 8) * 128);
        }
    };

    issueK(kbase);
    issueV(0, kbase);
    __syncthreads();

    #pragma unroll 1
    for (int it = 0; it < 16; ++it) {
        const int n0  = kbase + it * 64;
        const int buf = it & 1;
        // S1: prefetch V(t+1) (drains at bar after QK), QK + exp + Ps
        if (it + 1 < 16) issueV(buf ^ 1, n0 + 64);

        #pragma unroll
        for (int kh = 0; kh < 2; ++kh) {   // kt-halves cap s-liveness at 16 regs
            f32x4 s0[2], s1[2];
            #pragma unroll
            for (int k2 = 0; k2 < 2; ++k2) {
                s0[k2] = (f32x4){0.f, 0.f, 0.f, 0.f};
                s1[k2] = (f32x4){0.f, 0.f, 0.f, 0.f};
            }
            __builtin_amdgcn_s_setprio(1);
            #pragma unroll
            for (int c = 0; c < 8; ++c)
                #pragma unroll
                for (int k2 = 0; k2 < 2; ++k2) {
                    int kt = kh * 2 + k2;
                    bf16x8 bfr = *(const bf16x8*)(&Ks[(kt * 16 + c16) * 256 + (((c * 4 + quad) ^ swz) << 3)]);
                    s0[k2] = mfma16x16(qf[0][c], bfr, s0[k2]);
                    s1[k2] = mfma16x16(qf[1][c], bfr, s1[k2]);
                }
            __builtin_amdgcn_s_setprio(0);
            #pragma unroll
            for (int k2 = 0; k2 < 2; ++k2) {
                int kt = kh * 2 + k2;
                float biasv = (maskf[n0 + kt * 16 + c16] - 1.0f) * 1e9f;
                #pragma unroll
                for (int r = 0; r < 4; ++r) {
                    float p0 = __expf(s0[k2][r] + biasv);
                    float p1 = __expf(s1[k2][r] + biasv);
                    psum[0][r] += p0;
                    psum[1][r] += p1;
                    *(__bf16*)&Ps[(quad * 4 + r) * 72 + kt * 16 + c16] = (__bf16)p0;
                    *(__bf16*)&Ps[(16 + quad * 4 + r) * 72 + kt * 16 + c16] = (__bf16)p1;
                }
            }
        }
        __syncthreads();   // drains V(t+1); Ps visible

        // S2: prefetch K(t+1) (drains at loop-end bar), PV for both subtiles
        if (it + 1 < 16) issueK(n0 + 64);
        __builtin_amdgcn_s_setprio(1);
        #pragma unroll
        for (int kstep = 0; kstep < 2; ++kstep) {
            bf16x8 pf0 = *(const bf16x8*)(&Ps[c16 * 72 + kstep * 32 + quad * 8]);
            bf16x8 pf1 = *(const bf16x8*)(&Ps[(16 + c16) * 72 + kstep * 32 + quad * 8]);
            #pragma unroll
            for (int t = 0; t < 16; ++t) {
                bf16x8 vf = *(const bf16x8*)(&Vs[buf][(t * 16 + c16) * 64 + (((kstep * 4 + quad) ^ swz) << 3)]);
                o[0][t] = mfma16x16(pf0, vf, o[0][t]);
                o[1][t] = mfma16x16(pf1, vf, o[1][t]);
            }
        }
        __builtin_amdgcn_s_setprio(0);
        __syncthreads();   // drains K(t+1); all PV done before V(t+2) staging
    }

    #pragma unroll
    for (int sub = 0; sub < 2; ++sub) {
        float inv[4];
        #pragma unroll
        for (int r = 0; r < 4; ++r) {
            float tsum = psum[sub][r];
            tsum += __shfl_xor(tsum, 1);
            tsum += __shfl_xor(tsum, 2);
            tsum += __shfl_xor(tsum, 4);
            tsum += __shfl_xor(tsum, 8);
            if (c16 == 0)
                lbuf[(size_t)(ksp * NHEAD + head) * N_TOK + q0w + sub * 16 + quad * 4 + r] = tsum;
            inv[r] = 1.0f / tsum;
        }
        #pragma unroll
        for (int t = 0; t < 16; ++t)
            #pragma unroll
            for (int r = 0; r < 4; ++r) {
                float val = o[sub][t][r] * inv[r];
                Ob[(size_t)(q0w + sub * 16 + quad * 4 + r) * DMODEL + head * DHEAD + t * 16 + c16] = (__bf16)val;
            }
    }
}

// ---- combine: 4-way weighted (partials normalized, shared m=0 -> exact)
__global__ void combine_kernel(const __bf16* __restrict__ O0,
                               const __bf16* __restrict__ O1,
                               const __bf16* __restrict__ O2,
                               const __bf16* __restrict__ O3,
                               const float* __restrict__ lbuf,
                               __bf16* __restrict__ out)
{
    int idx  = blockIdx.x * 256 + threadIdx.x;
    int tok  = idx >> 7;
    int g    = idx & 127;
    int head = g >> 5;
    float l0 = lbuf[(size_t)(0 * NHEAD + head) * N_TOK + tok];
    float l1 = lbuf[(size_t)(1 * NHEAD + head) * N_TOK + tok];
    float l2 = lbuf[(size_t)(2 * NHEAD + head) * N_TOK + tok];
    float l3 = lbuf[(size_t)(3 * NHEAD + head) * N_TOK + tok];
    float inv = 1.0f / (l0 + l1 + l2 + l3);
    size_t off = (size_t)tok * DMODEL + g * 8;
    bf16x8 a = *(const bf16x8*)(O0 + off);
    bf16x8 b = *(const bf16x8*)(O1 + off);
    bf16x8 c = *(const bf16x8*)(O2 + off);
    bf16x8 dd = *(const bf16x8*)(O3 + off);
    bf16x8 z;
    #pragma unroll
    for (int j = 0; j < 8; ++j)
        z[j] = (__bf16)((l0 * (float)a[j] + l1 * (float)b[j] + l2 * (float)c[j] + l3 * (float)dd[j]) * inv);
    *(bf16x8*)(out + off) = z;
}

extern "C" void kernel_launch(void* const* d_in, const int* in_sizes, int n_in,
                              void* d_out, int out_size, void* d_ws, size_t ws_size,
                              hipStream_t stream)
{
    (void)in_sizes; (void)n_in; (void)out_size;
    const float* q  = (const float*)d_in[0];
    const float* k  = (const float*)d_in[1];
    const float* v  = (const float*)d_in[2];
    const float* w1 = (const float*)d_in[3];
    const float* b1 = (const float*)d_in[4];
    const float* w2 = (const float*)d_in[5];
    const float* b2 = (const float*)d_in[6];
    const float* wq = (const float*)d_in[7];
    const float* bq = (const float*)d_in[8];
    const float* wk = (const float*)d_in[9];
    const float* bk = (const float*)d_in[10];
    const float* wvw = (const float*)d_in[11];
    const float* bv = (const float*)d_in[12];
    const float* wo = (const float*)d_in[13];
    const float* bo = (const float*)d_in[14];

    if (ws_size < 35667968u + 8388608u + 131072u) return;  // proven floor (R5)

    char* ws = (char*)d_ws;
    float*  maskf = (float*)ws;                       // 16 KB
    __bf16* hbuf  = (__bf16*)(ws + 16384);            // 2 MB region: h -> lbuf -> woT
    float*  lbuf  = (float*)(ws + 16384);             // [4][4][4096] f32 = 256 KB
    __bf16* qp    = (__bf16*)(ws + 16384 + 2097152);  // 8 MB each
    __bf16* kpb   = qp  + 4194304;
    __bf16* vpT   = kpb + 4194304;                    // [1024][4096] via swapped V-gemm
    __bf16* ctx   = vpT + 4194304;                    // O0; kbf scratch before attn
    __bf16* O1    = (__bf16*)(ws + 35667968u);        // 8 MB; qbf scratch before attn

    // d_out (16 MB fp32) scratch, dead before final GEMM overwrites it:
    // wqT@0 | wkT@2M | wvT@4M | w1T@6M | vbf@6.5M..14.5M ; then O2@0, O3@8M
    __bf16* wqT = (__bf16*)d_out;
    __bf16* wkT = wqT + 1048576;
    __bf16* wvT = wkT + 1048576;
    __bf16* w1T = wvT + 1048576;
    __bf16* vbf = (__bf16*)((char*)d_out + 6815744u);
    __bf16* O2  = (__bf16*)d_out;                     // after fused projections
    __bf16* O3  = (__bf16*)((char*)d_out + 8388608u);
    __bf16* woT = hbuf;                               // written AFTER combine
    __bf16* qbf = O1;                                 // dead until attn writes O1
    __bf16* kbf = ctx;                                // dead until attn writes O0

    // 0) q,k,v -> bf16
    CvtArgs ca;
    ca.src[0] = q;  ca.dst[0] = qbf;
    ca.src[1] = k;  ca.dst[1] = kbf;
    ca.src[2] = v;  ca.dst[2] = vbf;
    cvt_bf16_kernel<<<dim3(2048, 3), 256, 0, stream>>>(ca);

    // 1) transpose w1,wq,wk,wv (one launch)
    TWArgs ta;
    ta.src[0] = w1;  ta.dst[0] = w1T;  ta.C[0] = 256;
    ta.src[1] = wq;  ta.dst[1] = wqT;  ta.C[1] = 1024;
    ta.src[2] = wk;  ta.dst[2] = wkT;  ta.C[2] = 1024;
    ta.src[3] = wvw; ta.dst[3] = wvT;  ta.C[3] = 1024;
    transposew_batch_kernel<<<dim3(16, 16, 4), 256, 0, stream>>>(ta);

    // 2) FUSED: h = relu(q@w1+b1) | qp = (q@wq)/16 | kp = k@wk | vpT = (v@wv)^T
    FusedArgs fa;
    fa.d[0] = { qbf, w1T, b1, hbuf, 1024, 1024,  256, 32,  64, 1, 0, 1.0f };
    fa.d[1] = { qbf, wqT, bq, qp,   1024, 1024, 1024, 32, 256, 0, 0, 0.0625f };
    fa.d[2] = { kbf, wkT, bk, kpb,  1024, 1024, 1024, 32, 256, 0, 0, 1.0f };
    fa.d[3] = { wvT, vbf, bv, vpT,  1024, 1024, 4096,  8, 256, 0, 1, 1.0f };
    gemm_fused<<<dim3(832), 256, 0, stream>>>(fa);

    // 3) mask (h dead after; lbuf reuses its region)
    score_mask_kernel<<<1024, 256, 0, stream>>>(hbuf, w2, b2, maskf);

    // 4) attention: 256 blocks x 512 thr, QBLK=256, 4 k-splits, XCD-clustered
    attn_kernel<<<dim3(256), 512, 0, stream>>>(qp, kpb, vpT, maskf, ctx, O1, O2, O3, lbuf);
    combine_kernel<<<2048, 256, 0, stream>>>(ctx, O1, O2, O3, lbuf, ctx);

    // 5) wo^T into hbuf (lbuf dead after combine), then out-projection
    transposew_kernel<<<dim3(16, 16), 256, 0, stream>>>(wo, woT, 1024);
    gemm_bt<float, false><<<dim3(32, 8), 256, 0, stream>>>(
        ctx, 1024, woT, 1024, bo, (float*)d_out, 1024, 1.0f, 0, maskf, 1024);
}